// Round 1
// baseline (357.741 us; speedup 1.0000x reference)
//
#include <hip/hip_runtime.h>
#include <math.h>

#define NV 4
#define NB 2
#define NC 32
#define ND 32
#define NH 128
#define NW 160
#define NG 8
#define HW (NH*NW)
#define NPIX (NB*NH*NW)

// ---------------------------------------------------------------------------
// Setup: per (b, v) compute P = M_src @ inv(M_ref), store rot(9)+trans(3).
// M = [[K3@E[:3,:4]],[0,0,0,1]]; inverse done analytically in double.
// M entries computed in f32 (matching the reference's f32 matmul), inversion
// in f64 so the result is the correctly-rounded inverse of the f32 matrix.
// ---------------------------------------------------------------------------
__global__ void proj_setup_kernel(const float* __restrict__ proj,
                                  float* __restrict__ pw) {
    int t = blockIdx.x * blockDim.x + threadIdx.x;
    if (t >= NB * NV) return;
    int b = t / NV, v = t % NV;
    const float* Eref = proj + ((b*(NV+1) + 0)*2 + 0)*16;
    const float* Kref = proj + ((b*(NV+1) + 0)*2 + 1)*16;
    const float* Esrc = proj + ((b*(NV+1) + (v+1))*2 + 0)*16;
    const float* Ksrc = proj + ((b*(NV+1) + (v+1))*2 + 1)*16;
    float Mr[12], Ms[12];
    for (int i = 0; i < 3; ++i)
        for (int j = 0; j < 4; ++j) {
            float sr = 0.f, ss = 0.f;
            for (int k = 0; k < 3; ++k) {
                sr += Kref[i*4+k] * Eref[k*4+j];
                ss += Ksrc[i*4+k] * Esrc[k*4+j];
            }
            Mr[i*4+j] = sr; Ms[i*4+j] = ss;
        }
    // A = Mr[:3,:3], a = Mr[:3,3]; inv([[A,a],[0,1]]) = [[Ai, -Ai a],[0,1]]
    double A[9], a[3];
    for (int i = 0; i < 3; ++i) {
        for (int j = 0; j < 3; ++j) A[i*3+j] = (double)Mr[i*4+j];
        a[i] = (double)Mr[i*4+3];
    }
    double c00 = A[4]*A[8]-A[5]*A[7];
    double c01 = A[5]*A[6]-A[3]*A[8];
    double c02 = A[3]*A[7]-A[4]*A[6];
    double det = A[0]*c00 + A[1]*c01 + A[2]*c02;
    double id  = 1.0/det;
    double Ai[9];
    Ai[0]=c00*id;                 Ai[1]=(A[2]*A[7]-A[1]*A[8])*id; Ai[2]=(A[1]*A[5]-A[2]*A[4])*id;
    Ai[3]=c01*id;                 Ai[4]=(A[0]*A[8]-A[2]*A[6])*id; Ai[5]=(A[2]*A[3]-A[0]*A[5])*id;
    Ai[6]=c02*id;                 Ai[7]=(A[1]*A[6]-A[0]*A[7])*id; Ai[8]=(A[0]*A[4]-A[1]*A[3])*id;
    double R[9], T[3];
    for (int i = 0; i < 3; ++i)
        for (int j = 0; j < 3; ++j) {
            double s = 0.0;
            for (int k = 0; k < 3; ++k) s += (double)Ms[i*4+k] * Ai[k*3+j];
            R[i*3+j] = s;
        }
    for (int i = 0; i < 3; ++i) {
        double s = (double)Ms[i*4+3];
        for (int k = 0; k < 3; ++k) s -= R[i*3+k]*a[k];
        T[i] = s;
    }
    float* o = pw + (b*NV + v)*12;
    for (int i = 0; i < 9; ++i) o[i]   = (float)R[i];
    for (int i = 0; i < 3; ++i) o[9+i] = (float)T[i];
}

// ---------------------------------------------------------------------------
// Main: thread = (pixel, depth). Half-wave (32 lanes) = one pixel's 32 depths.
// ---------------------------------------------------------------------------
__global__ __launch_bounds__(256) void mvs_kernel(
    const float* __restrict__ ref_feats,
    const float* __restrict__ src_feats,
    const float* __restrict__ depth_hypo,
    const float* __restrict__ w_reg,
    const float* __restrict__ pw,
    float* __restrict__ out)
{
    int tid = blockIdx.x * 256 + threadIdx.x;
    int d = threadIdx.x & 31;
    int p = tid >> 5;
    if (p >= NPIX) return;
    int w = p % NW;
    int h = (p / NW) % NH;
    int b = p / (NW*NH);
    float xf = (float)w, yf = (float)h;
    float depth = depth_hypo[((b*ND + d)*NH + h)*NW + w];

    float wr[NG];
    #pragma unroll
    for (int g = 0; g < NG; ++g) wr[g] = w_reg[g];

    float logacc = 0.f;
    float cwsum  = 1e-8f;   // cor_weight_sum init

    for (int v = 0; v < NV; ++v) {
        const float* RT = pw + (b*NV + v)*12;
        // geometry in double: correctly-rounded px/py (argmax-tie safety)
        double dd  = (double)depth;
        double px_ = ((double)RT[0]*(double)xf + (double)RT[1]*(double)yf + (double)RT[2])*dd + (double)RT[9];
        double py_ = ((double)RT[3]*(double)xf + (double)RT[4]*(double)yf + (double)RT[5])*dd + (double)RT[10];
        double pz_ = ((double)RT[6]*(double)xf + (double)RT[7]*(double)yf + (double)RT[8])*dd + (double)RT[11];
        if (pz_ == 0.0) pz_ = 1e-9;
        double pxd = px_/pz_, pyd = py_/pz_;
        double x0d = floor(pxd), y0d = floor(pyd);
        int x0i = (int)x0d, y0i = (int)y0d;
        int x1i = x0i + 1,  y1i = y0i + 1;
        float wx = (float)(pxd - x0d), wy = (float)(pyd - y0d);

        float vx0 = (x0i >= 0 && x0i < NW) ? 1.f : 0.f;
        float vx1 = (x1i >= 0 && x1i < NW) ? 1.f : 0.f;
        float vy0 = (y0i >= 0 && y0i < NH) ? 1.f : 0.f;
        float vy1 = (y1i >= 0 && y1i < NH) ? 1.f : 0.f;
        float w00 = (1.f-wx)*(1.f-wy) * vx0*vy0;
        float w01 = wx*(1.f-wy)       * vx1*vy0;
        float w10 = (1.f-wx)*wy       * vx0*vy1;
        float w11 = wx*wy             * vx1*vy1;
        int xc0 = min(max(x0i,0),NW-1), xc1 = min(max(x1i,0),NW-1);
        int yc0 = min(max(y0i,0),NH-1), yc1 = min(max(y1i,0),NH-1);
        int i00 = yc0*NW+xc0, i01 = yc0*NW+xc1;
        int i10 = yc1*NW+xc0, i11 = yc1*NW+xc1;

        const float* sb = src_feats + ((v*NB + b)*NC)*HW;
        const float* rb = ref_feats + ((v*NB + b)*NC)*HW + h*NW + w;

        float acc[NG];
        #pragma unroll
        for (int g = 0; g < NG; ++g) acc[g] = 0.f;
        #pragma unroll
        for (int c = 0; c < NC; ++c) {   // full unroll: acc index static
            const float* scp = sb + c*HW;
            float f = w00*scp[i00] + w01*scp[i01] + w10*scp[i10] + w11*scp[i11];
            acc[c>>2] += f * rb[c*HW];
        }
        float s = 0.f, t = 0.f;
        #pragma unroll
        for (int g = 0; g < NG; ++g) {
            float cf = 0.25f*acc[g];   // mean over C/G=4
            s += cf;
            t += cf*wr[g];
        }
        // cor_weight = max(softmax_D(s)) = 1/sum(exp(s - max))
        float m = s;
        #pragma unroll
        for (int mask = 1; mask < 32; mask <<= 1)
            m = fmaxf(m, __shfl_xor(m, mask, 32));
        float e = expf(s - m);
        float Z = e;
        #pragma unroll
        for (int mask = 1; mask < 32; mask <<= 1)
            Z += __shfl_xor(Z, mask, 32);
        float cw = 1.f / Z;
        logacc += cw * t;
        cwsum  += cw;
    }

    float logit = logacc / (cwsum + 1e-7f);
    // softmax over 32 depths
    float m2 = logit;
    #pragma unroll
    for (int mask = 1; mask < 32; mask <<= 1)
        m2 = fmaxf(m2, __shfl_xor(m2, mask, 32));
    float e2 = expf(logit - m2);
    float Z2 = e2;
    #pragma unroll
    for (int mask = 1; mask < 32; mask <<= 1)
        Z2 += __shfl_xor(Z2, mask, 32);
    float aw = e2 / Z2;
    out[NPIX + ((b*ND + d)*NH + h)*NW + w] = aw;

    // argmax over depth (first-index tiebreak), then pick depth_hypo there
    float bv = aw; int bi = d;
    #pragma unroll
    for (int mask = 1; mask < 32; mask <<= 1) {
        float ov = __shfl_xor(bv, mask, 32);
        int   oi = __shfl_xor(bi, mask, 32);
        if (ov > bv || (ov == bv && oi < bi)) { bv = ov; bi = oi; }
    }
    float dsel = __shfl(depth, bi, 32);
    if (d == 0) out[p] = dsel;
}

extern "C" void kernel_launch(void* const* d_in, const int* in_sizes, int n_in,
                              void* d_out, int out_size, void* d_ws, size_t ws_size,
                              hipStream_t stream) {
    const float* ref_feats  = (const float*)d_in[0];
    const float* src_feats  = (const float*)d_in[1];
    const float* proj       = (const float*)d_in[2];
    const float* depth_hypo = (const float*)d_in[3];
    const float* w_reg      = (const float*)d_in[4];
    float* out = (float*)d_out;
    float* pw  = (float*)d_ws;   // 96 floats of rot/trans per (b,v)

    hipLaunchKernelGGL(proj_setup_kernel, dim3(1), dim3(64), 0, stream, proj, pw);
    hipLaunchKernelGGL(mvs_kernel, dim3((NPIX*ND)/256), dim3(256), 0, stream,
                       ref_feats, src_feats, depth_hypo, w_reg, pw, out);
}

// Round 2
// 183.867 us; speedup vs baseline: 1.9456x; 1.9456x over previous
//
#include <hip/hip_runtime.h>
#include <math.h>

#define NV 4
#define NB 2
#define NC 32
#define ND 32
#define NH 128
#define NW 160
#define NG 8
#define HW (NH*NW)
#define NPIX (NB*NH*NW)
#define FEATSZ (NV*NB*HW*NC)   // elements in one feature tensor

// ---------------------------------------------------------------------------
// proj setup (unchanged from round 0)
// ---------------------------------------------------------------------------
__global__ void proj_setup_kernel(const float* __restrict__ proj,
                                  float* __restrict__ pw) {
    int t = blockIdx.x * blockDim.x + threadIdx.x;
    if (t >= NB * NV) return;
    int b = t / NV, v = t % NV;
    const float* Eref = proj + ((b*(NV+1) + 0)*2 + 0)*16;
    const float* Kref = proj + ((b*(NV+1) + 0)*2 + 1)*16;
    const float* Esrc = proj + ((b*(NV+1) + (v+1))*2 + 0)*16;
    const float* Ksrc = proj + ((b*(NV+1) + (v+1))*2 + 1)*16;
    float Mr[12], Ms[12];
    for (int i = 0; i < 3; ++i)
        for (int j = 0; j < 4; ++j) {
            float sr = 0.f, ss = 0.f;
            for (int k = 0; k < 3; ++k) {
                sr += Kref[i*4+k] * Eref[k*4+j];
                ss += Ksrc[i*4+k] * Esrc[k*4+j];
            }
            Mr[i*4+j] = sr; Ms[i*4+j] = ss;
        }
    double A[9], a[3];
    for (int i = 0; i < 3; ++i) {
        for (int j = 0; j < 3; ++j) A[i*3+j] = (double)Mr[i*4+j];
        a[i] = (double)Mr[i*4+3];
    }
    double c00 = A[4]*A[8]-A[5]*A[7];
    double c01 = A[5]*A[6]-A[3]*A[8];
    double c02 = A[3]*A[7]-A[4]*A[6];
    double det = A[0]*c00 + A[1]*c01 + A[2]*c02;
    double id  = 1.0/det;
    double Ai[9];
    Ai[0]=c00*id;                 Ai[1]=(A[2]*A[7]-A[1]*A[8])*id; Ai[2]=(A[1]*A[5]-A[2]*A[4])*id;
    Ai[3]=c01*id;                 Ai[4]=(A[0]*A[8]-A[2]*A[6])*id; Ai[5]=(A[2]*A[3]-A[0]*A[5])*id;
    Ai[6]=c02*id;                 Ai[7]=(A[1]*A[6]-A[0]*A[7])*id; Ai[8]=(A[0]*A[4]-A[1]*A[3])*id;
    double R[9], T[3];
    for (int i = 0; i < 3; ++i)
        for (int j = 0; j < 3; ++j) {
            double s = 0.0;
            for (int k = 0; k < 3; ++k) s += (double)Ms[i*4+k] * Ai[k*3+j];
            R[i*3+j] = s;
        }
    for (int i = 0; i < 3; ++i) {
        double s = (double)Ms[i*4+3];
        for (int k = 0; k < 3; ++k) s -= R[i*3+k]*a[k];
        T[i] = s;
    }
    float* o = pw + (b*NV + v)*12;
    for (int i = 0; i < 9; ++i) o[i]   = (float)R[i];
    for (int i = 0; i < 3; ++i) o[9+i] = (float)T[i];
}

// ---------------------------------------------------------------------------
// LDS-tiled transpose: [vb][c][hw] -> [vb][hw][c].  Tile 32c x 64hw.
// Read coalesced along hw, write coalesced along c. lds padded +1.
// ---------------------------------------------------------------------------
__global__ __launch_bounds__(256) void transpose_kernel(
    const float* __restrict__ in, float* __restrict__ out) {
    __shared__ float lds[NC][65];
    int vb = blockIdx.y;
    int hwbase = blockIdx.x * 64;
    int t = threadIdx.x;
    #pragma unroll
    for (int r = 0; r < 8; ++r) {
        int c  = (t >> 6) + r*4;     // 0..31
        int hw = t & 63;
        lds[c][hw] = in[(vb*NC + c)*HW + hwbase + hw];
    }
    __syncthreads();
    #pragma unroll
    for (int r = 0; r < 8; ++r) {
        int c  = t & 31;
        int hw = (t >> 5) + r*8;     // 0..63
        out[((size_t)vb*HW + hwbase + hw)*NC + c] = lds[c][hw];
    }
}

// ---------------------------------------------------------------------------
// Main (channels-last): thread = (pixel, depth); half-wave = 32 depths.
// FP accumulation order identical to round 0 (c ascending, g = c>>2 = j).
// ---------------------------------------------------------------------------
__global__ __launch_bounds__(256) void mvs_kernel_t(
    const float* __restrict__ refT,
    const float* __restrict__ srcT,
    const float* __restrict__ depth_hypo,
    const float* __restrict__ w_reg,
    const float* __restrict__ pw,
    float* __restrict__ out)
{
    int tid = blockIdx.x * 256 + threadIdx.x;
    int d = threadIdx.x & 31;
    int p = tid >> 5;
    if (p >= NPIX) return;
    int w = p % NW;
    int h = (p / NW) % NH;
    int b = p / (NW*NH);
    float xf = (float)w, yf = (float)h;
    float depth = depth_hypo[((b*ND + d)*NH + h)*NW + w];

    float wr[NG];
    #pragma unroll
    for (int g = 0; g < NG; ++g) wr[g] = w_reg[g];

    float logacc = 0.f;
    float cwsum  = 1e-8f;

    for (int v = 0; v < NV; ++v) {
        const float* RT = pw + (b*NV + v)*12;
        double dd  = (double)depth;
        double px_ = ((double)RT[0]*(double)xf + (double)RT[1]*(double)yf + (double)RT[2])*dd + (double)RT[9];
        double py_ = ((double)RT[3]*(double)xf + (double)RT[4]*(double)yf + (double)RT[5])*dd + (double)RT[10];
        double pz_ = ((double)RT[6]*(double)xf + (double)RT[7]*(double)yf + (double)RT[8])*dd + (double)RT[11];
        if (pz_ == 0.0) pz_ = 1e-9;
        double pxd = px_/pz_, pyd = py_/pz_;
        double x0d = floor(pxd), y0d = floor(pyd);
        int x0i = (int)x0d, y0i = (int)y0d;
        int x1i = x0i + 1,  y1i = y0i + 1;
        float wx = (float)(pxd - x0d), wy = (float)(pyd - y0d);

        float vx0 = (x0i >= 0 && x0i < NW) ? 1.f : 0.f;
        float vx1 = (x1i >= 0 && x1i < NW) ? 1.f : 0.f;
        float vy0 = (y0i >= 0 && y0i < NH) ? 1.f : 0.f;
        float vy1 = (y1i >= 0 && y1i < NH) ? 1.f : 0.f;
        float w00 = (1.f-wx)*(1.f-wy) * vx0*vy0;
        float w01 = wx*(1.f-wy)       * vx1*vy0;
        float w10 = (1.f-wx)*wy       * vx0*vy1;
        float w11 = wx*wy             * vx1*vy1;
        int xc0 = min(max(x0i,0),NW-1), xc1 = min(max(x1i,0),NW-1);
        int yc0 = min(max(y0i,0),NH-1), yc1 = min(max(y1i,0),NH-1);
        // channels-last float4 bases (in float4 units: pixel*NC/4)
        int vb = v*NB + b;
        const float4* s00 = (const float4*)(srcT + ((size_t)vb*HW + yc0*NW+xc0)*NC);
        const float4* s01 = (const float4*)(srcT + ((size_t)vb*HW + yc0*NW+xc1)*NC);
        const float4* s10 = (const float4*)(srcT + ((size_t)vb*HW + yc1*NW+xc0)*NC);
        const float4* s11 = (const float4*)(srcT + ((size_t)vb*HW + yc1*NW+xc1)*NC);
        const float4* rr  = (const float4*)(refT + ((size_t)vb*HW + h*NW+w)*NC);

        float s = 0.f, t = 0.f;
        #pragma unroll
        for (int j = 0; j < NG; ++j) {       // group j == float4 chunk j
            float4 a00 = s00[j], a01 = s01[j], a10 = s10[j], a11 = s11[j];
            float4 rf  = rr[j];
            float acc = 0.f;
            {   // c = 4j+0..3, same order as round 0
                float f0 = w00*a00.x + w01*a01.x + w10*a10.x + w11*a11.x;
                acc += f0*rf.x;
                float f1 = w00*a00.y + w01*a01.y + w10*a10.y + w11*a11.y;
                acc += f1*rf.y;
                float f2 = w00*a00.z + w01*a01.z + w10*a10.z + w11*a11.z;
                acc += f2*rf.z;
                float f3 = w00*a00.w + w01*a01.w + w10*a10.w + w11*a11.w;
                acc += f3*rf.w;
            }
            float cf = 0.25f*acc;
            s += cf;
            t += cf*wr[j];
        }
        float m = s;
        #pragma unroll
        for (int mask = 1; mask < 32; mask <<= 1)
            m = fmaxf(m, __shfl_xor(m, mask, 32));
        float e = expf(s - m);
        float Z = e;
        #pragma unroll
        for (int mask = 1; mask < 32; mask <<= 1)
            Z += __shfl_xor(Z, mask, 32);
        float cw = 1.f / Z;
        logacc += cw * t;
        cwsum  += cw;
    }

    float logit = logacc / (cwsum + 1e-7f);
    float m2 = logit;
    #pragma unroll
    for (int mask = 1; mask < 32; mask <<= 1)
        m2 = fmaxf(m2, __shfl_xor(m2, mask, 32));
    float e2 = expf(logit - m2);
    float Z2 = e2;
    #pragma unroll
    for (int mask = 1; mask < 32; mask <<= 1)
        Z2 += __shfl_xor(Z2, mask, 32);
    float aw = e2 / Z2;
    out[NPIX + ((b*ND + d)*NH + h)*NW + w] = aw;

    float bv = aw; int bi = d;
    #pragma unroll
    for (int mask = 1; mask < 32; mask <<= 1) {
        float ov = __shfl_xor(bv, mask, 32);
        int   oi = __shfl_xor(bi, mask, 32);
        if (ov > bv || (ov == bv && oi < bi)) { bv = ov; bi = oi; }
    }
    float dsel = __shfl(depth, bi, 32);
    if (d == 0) out[p] = dsel;
}

// ---------------------------------------------------------------------------
// Fallback (round-0 kernel, original layout) if ws too small for transposes.
// ---------------------------------------------------------------------------
__global__ __launch_bounds__(256) void mvs_kernel(
    const float* __restrict__ ref_feats,
    const float* __restrict__ src_feats,
    const float* __restrict__ depth_hypo,
    const float* __restrict__ w_reg,
    const float* __restrict__ pw,
    float* __restrict__ out)
{
    int tid = blockIdx.x * 256 + threadIdx.x;
    int d = threadIdx.x & 31;
    int p = tid >> 5;
    if (p >= NPIX) return;
    int w = p % NW;
    int h = (p / NW) % NH;
    int b = p / (NW*NH);
    float xf = (float)w, yf = (float)h;
    float depth = depth_hypo[((b*ND + d)*NH + h)*NW + w];
    float wr[NG];
    #pragma unroll
    for (int g = 0; g < NG; ++g) wr[g] = w_reg[g];
    float logacc = 0.f;
    float cwsum  = 1e-8f;
    for (int v = 0; v < NV; ++v) {
        const float* RT = pw + (b*NV + v)*12;
        double dd  = (double)depth;
        double px_ = ((double)RT[0]*(double)xf + (double)RT[1]*(double)yf + (double)RT[2])*dd + (double)RT[9];
        double py_ = ((double)RT[3]*(double)xf + (double)RT[4]*(double)yf + (double)RT[5])*dd + (double)RT[10];
        double pz_ = ((double)RT[6]*(double)xf + (double)RT[7]*(double)yf + (double)RT[8])*dd + (double)RT[11];
        if (pz_ == 0.0) pz_ = 1e-9;
        double pxd = px_/pz_, pyd = py_/pz_;
        double x0d = floor(pxd), y0d = floor(pyd);
        int x0i = (int)x0d, y0i = (int)y0d;
        int x1i = x0i + 1,  y1i = y0i + 1;
        float wx = (float)(pxd - x0d), wy = (float)(pyd - y0d);
        float vx0 = (x0i >= 0 && x0i < NW) ? 1.f : 0.f;
        float vx1 = (x1i >= 0 && x1i < NW) ? 1.f : 0.f;
        float vy0 = (y0i >= 0 && y0i < NH) ? 1.f : 0.f;
        float vy1 = (y1i >= 0 && y1i < NH) ? 1.f : 0.f;
        float w00 = (1.f-wx)*(1.f-wy) * vx0*vy0;
        float w01 = wx*(1.f-wy)       * vx1*vy0;
        float w10 = (1.f-wx)*wy       * vx0*vy1;
        float w11 = wx*wy             * vx1*vy1;
        int xc0 = min(max(x0i,0),NW-1), xc1 = min(max(x1i,0),NW-1);
        int yc0 = min(max(y0i,0),NH-1), yc1 = min(max(y1i,0),NH-1);
        int i00 = yc0*NW+xc0, i01 = yc0*NW+xc1;
        int i10 = yc1*NW+xc0, i11 = yc1*NW+xc1;
        const float* sb = src_feats + ((v*NB + b)*NC)*HW;
        const float* rb = ref_feats + ((v*NB + b)*NC)*HW + h*NW + w;
        float acc[NG];
        #pragma unroll
        for (int g = 0; g < NG; ++g) acc[g] = 0.f;
        #pragma unroll
        for (int c = 0; c < NC; ++c) {
            const float* scp = sb + c*HW;
            float f = w00*scp[i00] + w01*scp[i01] + w10*scp[i10] + w11*scp[i11];
            acc[c>>2] += f * rb[c*HW];
        }
        float s = 0.f, t = 0.f;
        #pragma unroll
        for (int g = 0; g < NG; ++g) {
            float cf = 0.25f*acc[g];
            s += cf;
            t += cf*wr[g];
        }
        float m = s;
        #pragma unroll
        for (int mask = 1; mask < 32; mask <<= 1)
            m = fmaxf(m, __shfl_xor(m, mask, 32));
        float e = expf(s - m);
        float Z = e;
        #pragma unroll
        for (int mask = 1; mask < 32; mask <<= 1)
            Z += __shfl_xor(Z, mask, 32);
        float cw = 1.f / Z;
        logacc += cw * t;
        cwsum  += cw;
    }
    float logit = logacc / (cwsum + 1e-7f);
    float m2 = logit;
    #pragma unroll
    for (int mask = 1; mask < 32; mask <<= 1)
        m2 = fmaxf(m2, __shfl_xor(m2, mask, 32));
    float e2 = expf(logit - m2);
    float Z2 = e2;
    #pragma unroll
    for (int mask = 1; mask < 32; mask <<= 1)
        Z2 += __shfl_xor(Z2, mask, 32);
    float aw = e2 / Z2;
    out[NPIX + ((b*ND + d)*NH + h)*NW + w] = aw;
    float bv = aw; int bi = d;
    #pragma unroll
    for (int mask = 1; mask < 32; mask <<= 1) {
        float ov = __shfl_xor(bv, mask, 32);
        int   oi = __shfl_xor(bi, mask, 32);
        if (ov > bv || (ov == bv && oi < bi)) { bv = ov; bi = oi; }
    }
    float dsel = __shfl(depth, bi, 32);
    if (d == 0) out[p] = dsel;
}

extern "C" void kernel_launch(void* const* d_in, const int* in_sizes, int n_in,
                              void* d_out, int out_size, void* d_ws, size_t ws_size,
                              hipStream_t stream) {
    const float* ref_feats  = (const float*)d_in[0];
    const float* src_feats  = (const float*)d_in[1];
    const float* proj       = (const float*)d_in[2];
    const float* depth_hypo = (const float*)d_in[3];
    const float* w_reg      = (const float*)d_in[4];
    float* out = (float*)d_out;

    size_t need = (size_t)2*FEATSZ*sizeof(float) + 96*sizeof(float);
    if (ws_size >= need) {
        float* srcT = (float*)d_ws;
        float* refT = srcT + FEATSZ;
        float* pw   = refT + FEATSZ;
        hipLaunchKernelGGL(proj_setup_kernel, dim3(1), dim3(64), 0, stream, proj, pw);
        dim3 tg(HW/64, NV*NB);
        hipLaunchKernelGGL(transpose_kernel, tg, dim3(256), 0, stream, src_feats, srcT);
        hipLaunchKernelGGL(transpose_kernel, tg, dim3(256), 0, stream, ref_feats, refT);
        hipLaunchKernelGGL(mvs_kernel_t, dim3((NPIX*ND)/256), dim3(256), 0, stream,
                           refT, srcT, depth_hypo, w_reg, pw, out);
    } else {
        float* pw = (float*)d_ws;
        hipLaunchKernelGGL(proj_setup_kernel, dim3(1), dim3(64), 0, stream, proj, pw);
        hipLaunchKernelGGL(mvs_kernel, dim3((NPIX*ND)/256), dim3(256), 0, stream,
                           ref_feats, src_feats, depth_hypo, w_reg, pw, out);
    }
}

// Round 3
// 179.319 us; speedup vs baseline: 1.9950x; 1.0254x over previous
//
#include <hip/hip_runtime.h>
#include <math.h>

#define NV 4
#define NB 2
#define NC 32
#define ND 32
#define NH 128
#define NW 160
#define NG 8
#define HW (NH*NW)
#define NPIX (NB*NH*NW)
#define FEATSZ (NV*NB*HW*NC)

#define BOXW 22
#define BOXH 9
#define P4   199          // padded plane stride (float4 units), odd -> bank spread

// ---------------------------------------------------------------------------
// proj setup (unchanged)
// ---------------------------------------------------------------------------
__global__ void proj_setup_kernel(const float* __restrict__ proj,
                                  float* __restrict__ pw) {
    int t = blockIdx.x * blockDim.x + threadIdx.x;
    if (t >= NB * NV) return;
    int b = t / NV, v = t % NV;
    const float* Eref = proj + ((b*(NV+1) + 0)*2 + 0)*16;
    const float* Kref = proj + ((b*(NV+1) + 0)*2 + 1)*16;
    const float* Esrc = proj + ((b*(NV+1) + (v+1))*2 + 0)*16;
    const float* Ksrc = proj + ((b*(NV+1) + (v+1))*2 + 1)*16;
    float Mr[12], Ms[12];
    for (int i = 0; i < 3; ++i)
        for (int j = 0; j < 4; ++j) {
            float sr = 0.f, ss = 0.f;
            for (int k = 0; k < 3; ++k) {
                sr += Kref[i*4+k] * Eref[k*4+j];
                ss += Ksrc[i*4+k] * Esrc[k*4+j];
            }
            Mr[i*4+j] = sr; Ms[i*4+j] = ss;
        }
    double A[9], a[3];
    for (int i = 0; i < 3; ++i) {
        for (int j = 0; j < 3; ++j) A[i*3+j] = (double)Mr[i*4+j];
        a[i] = (double)Mr[i*4+3];
    }
    double c00 = A[4]*A[8]-A[5]*A[7];
    double c01 = A[5]*A[6]-A[3]*A[8];
    double c02 = A[3]*A[7]-A[4]*A[6];
    double det = A[0]*c00 + A[1]*c01 + A[2]*c02;
    double id  = 1.0/det;
    double Ai[9];
    Ai[0]=c00*id;                 Ai[1]=(A[2]*A[7]-A[1]*A[8])*id; Ai[2]=(A[1]*A[5]-A[2]*A[4])*id;
    Ai[3]=c01*id;                 Ai[4]=(A[0]*A[8]-A[2]*A[6])*id; Ai[5]=(A[2]*A[3]-A[0]*A[5])*id;
    Ai[6]=c02*id;                 Ai[7]=(A[1]*A[6]-A[0]*A[7])*id; Ai[8]=(A[0]*A[4]-A[1]*A[3])*id;
    double R[9], T[3];
    for (int i = 0; i < 3; ++i)
        for (int j = 0; j < 3; ++j) {
            double s = 0.0;
            for (int k = 0; k < 3; ++k) s += (double)Ms[i*4+k] * Ai[k*3+j];
            R[i*3+j] = s;
        }
    for (int i = 0; i < 3; ++i) {
        double s = (double)Ms[i*4+3];
        for (int k = 0; k < 3; ++k) s -= R[i*3+k]*a[k];
        T[i] = s;
    }
    float* o = pw + (b*NV + v)*12;
    for (int i = 0; i < 9; ++i) o[i]   = (float)R[i];
    for (int i = 0; i < 3; ++i) o[9+i] = (float)T[i];
}

// ---------------------------------------------------------------------------
// LDS-tiled transpose: [vb][c][hw] -> [vb][hw][c] (unchanged)
// ---------------------------------------------------------------------------
__global__ __launch_bounds__(256) void transpose_kernel(
    const float* __restrict__ in, float* __restrict__ out) {
    __shared__ float lds[NC][65];
    int vb = blockIdx.y;
    int hwbase = blockIdx.x * 64;
    int t = threadIdx.x;
    #pragma unroll
    for (int r = 0; r < 8; ++r) {
        int c  = (t >> 6) + r*4;
        int hw = t & 63;
        lds[c][hw] = in[(vb*NC + c)*HW + hwbase + hw];
    }
    __syncthreads();
    #pragma unroll
    for (int r = 0; r < 8; ++r) {
        int c  = t & 31;
        int hw = (t >> 5) + r*8;
        out[((size_t)vb*HW + hwbase + hw)*NC + c] = lds[c][hw];
    }
}

// ---------------------------------------------------------------------------
// Main: thread=(pixel,depth); half-wave = one pixel's 32 depths; block = 8
// consecutive pixels in one row. Per (block,view): reduce tap bounding box,
// stage box into LDS (coalesced), taps become ds_read_b128 with compile-time
// plane offsets. FP math bit-identical to the global-gather version.
// ---------------------------------------------------------------------------
__global__ __launch_bounds__(256) void mvs_kernel_t(
    const float* __restrict__ refT,
    const float* __restrict__ srcT,
    const float* __restrict__ depth_hypo,
    const float* __restrict__ w_reg,
    const float* __restrict__ pw,
    float* __restrict__ out)
{
    __shared__ float4 box4[8*P4];        // 8 chunk planes, stride P4
    __shared__ int redmnx[4], redmxx[4], redmny[4], redmxy[4];

    int tid = blockIdx.x * 256 + threadIdx.x;
    int d = threadIdx.x & 31;
    int p = tid >> 5;
    int w = p % NW;
    int h = (p / NW) % NH;
    int b = p / (NW*NH);
    float xf = (float)w, yf = (float)h;
    float depth = depth_hypo[((b*ND + d)*NH + h)*NW + w];

    float wr[NG];
    #pragma unroll
    for (int g = 0; g < NG; ++g) wr[g] = w_reg[g];

    float logacc = 0.f;
    float cwsum  = 1e-8f;

    for (int v = 0; v < NV; ++v) {
        const float* RT = pw + (b*NV + v)*12;
        double dd  = (double)depth;
        double px_ = ((double)RT[0]*(double)xf + (double)RT[1]*(double)yf + (double)RT[2])*dd + (double)RT[9];
        double py_ = ((double)RT[3]*(double)xf + (double)RT[4]*(double)yf + (double)RT[5])*dd + (double)RT[10];
        double pz_ = ((double)RT[6]*(double)xf + (double)RT[7]*(double)yf + (double)RT[8])*dd + (double)RT[11];
        if (pz_ == 0.0) pz_ = 1e-9;
        double pxd = px_/pz_, pyd = py_/pz_;
        double x0d = floor(pxd), y0d = floor(pyd);
        int x0i = (int)x0d, y0i = (int)y0d;
        int x1i = x0i + 1,  y1i = y0i + 1;
        float wx = (float)(pxd - x0d), wy = (float)(pyd - y0d);

        float vx0 = (x0i >= 0 && x0i < NW) ? 1.f : 0.f;
        float vx1 = (x1i >= 0 && x1i < NW) ? 1.f : 0.f;
        float vy0 = (y0i >= 0 && y0i < NH) ? 1.f : 0.f;
        float vy1 = (y1i >= 0 && y1i < NH) ? 1.f : 0.f;
        float w00 = (1.f-wx)*(1.f-wy) * vx0*vy0;
        float w01 = wx*(1.f-wy)       * vx1*vy0;
        float w10 = (1.f-wx)*wy       * vx0*vy1;
        float w11 = wx*wy             * vx1*vy1;
        int xc0 = min(max(x0i,0),NW-1), xc1 = min(max(x1i,0),NW-1);
        int yc0 = min(max(y0i,0),NH-1), yc1 = min(max(y1i,0),NH-1);
        int vb = v*NB + b;

        // ---- block bounding box of clamped taps ----
        int mnx = xc0, mxx = xc1, mny = yc0, mxy = yc1;
        #pragma unroll
        for (int m = 1; m < 64; m <<= 1) {
            mnx = min(mnx, __shfl_xor(mnx, m, 64));
            mxx = max(mxx, __shfl_xor(mxx, m, 64));
            mny = min(mny, __shfl_xor(mny, m, 64));
            mxy = max(mxy, __shfl_xor(mxy, m, 64));
        }
        int wid = threadIdx.x >> 6;
        if ((threadIdx.x & 63) == 0) {
            redmnx[wid] = mnx; redmxx[wid] = mxx;
            redmny[wid] = mny; redmxy[wid] = mxy;
        }
        __syncthreads();
        int x0b = min(min(redmnx[0],redmnx[1]), min(redmnx[2],redmnx[3]));
        int x1b = max(max(redmxx[0],redmxx[1]), max(redmxx[2],redmxx[3]));
        int y0b = min(min(redmny[0],redmny[1]), min(redmny[2],redmny[3]));
        int y1b = max(max(redmxy[0],redmxy[1]), max(redmxy[2],redmxy[3]));
        int bw = x1b - x0b + 1;
        int bh = y1b - y0b + 1;
        bool fit = (bw <= BOXW) && (bh <= BOXH);

        if (fit) {
            const float4* gsrc = (const float4*)(srcT + ((size_t)vb*HW + (size_t)y0b*NW + x0b)*NC);
            int rowlen = bw*8;
            for (int yy = 0; yy < bh; ++yy) {
                for (int n = threadIdx.x; n < rowlen; n += 256) {
                    int ii = n >> 3, jj = n & 7;
                    box4[jj*P4 + yy*bw + ii] = gsrc[yy*(NW*NC/4) + n];
                }
            }
        }
        __syncthreads();

        const float4* rr = (const float4*)(refT + ((size_t)vb*HW + h*NW + w)*NC);
        float s = 0.f, t = 0.f;
        if (fit) {
            int b00 = (yc0 - y0b)*bw + (xc0 - x0b);
            int b01 = (yc0 - y0b)*bw + (xc1 - x0b);
            int b10 = (yc1 - y0b)*bw + (xc0 - x0b);
            int b11 = (yc1 - y0b)*bw + (xc1 - x0b);
            #pragma unroll
            for (int j = 0; j < NG; ++j) {
                float4 a00 = box4[j*P4 + b00];
                float4 a01 = box4[j*P4 + b01];
                float4 a10 = box4[j*P4 + b10];
                float4 a11 = box4[j*P4 + b11];
                float4 rf  = rr[j];
                float acc = 0.f;
                float f0 = w00*a00.x + w01*a01.x + w10*a10.x + w11*a11.x;
                acc += f0*rf.x;
                float f1 = w00*a00.y + w01*a01.y + w10*a10.y + w11*a11.y;
                acc += f1*rf.y;
                float f2 = w00*a00.z + w01*a01.z + w10*a10.z + w11*a11.z;
                acc += f2*rf.z;
                float f3 = w00*a00.w + w01*a01.w + w10*a10.w + w11*a11.w;
                acc += f3*rf.w;
                float cf = 0.25f*acc;
                s += cf;
                t += cf*wr[j];
            }
        } else {
            int i00 = yc0*NW+xc0, i01 = yc0*NW+xc1;
            int i10 = yc1*NW+xc0, i11 = yc1*NW+xc1;
            const float4* s00 = (const float4*)(srcT + ((size_t)vb*HW + i00)*NC);
            const float4* s01 = (const float4*)(srcT + ((size_t)vb*HW + i01)*NC);
            const float4* s10 = (const float4*)(srcT + ((size_t)vb*HW + i10)*NC);
            const float4* s11 = (const float4*)(srcT + ((size_t)vb*HW + i11)*NC);
            #pragma unroll
            for (int j = 0; j < NG; ++j) {
                float4 a00 = s00[j], a01 = s01[j], a10 = s10[j], a11 = s11[j];
                float4 rf  = rr[j];
                float acc = 0.f;
                float f0 = w00*a00.x + w01*a01.x + w10*a10.x + w11*a11.x;
                acc += f0*rf.x;
                float f1 = w00*a00.y + w01*a01.y + w10*a10.y + w11*a11.y;
                acc += f1*rf.y;
                float f2 = w00*a00.z + w01*a01.z + w10*a10.z + w11*a11.z;
                acc += f2*rf.z;
                float f3 = w00*a00.w + w01*a01.w + w10*a10.w + w11*a11.w;
                acc += f3*rf.w;
                float cf = 0.25f*acc;
                s += cf;
                t += cf*wr[j];
            }
        }

        float m = s;
        #pragma unroll
        for (int mask = 1; mask < 32; mask <<= 1)
            m = fmaxf(m, __shfl_xor(m, mask, 32));
        float e = expf(s - m);
        float Z = e;
        #pragma unroll
        for (int mask = 1; mask < 32; mask <<= 1)
            Z += __shfl_xor(Z, mask, 32);
        float cw = 1.f / Z;
        logacc += cw * t;
        cwsum  += cw;
    }

    float logit = logacc / (cwsum + 1e-7f);
    float m2 = logit;
    #pragma unroll
    for (int mask = 1; mask < 32; mask <<= 1)
        m2 = fmaxf(m2, __shfl_xor(m2, mask, 32));
    float e2 = expf(logit - m2);
    float Z2 = e2;
    #pragma unroll
    for (int mask = 1; mask < 32; mask <<= 1)
        Z2 += __shfl_xor(Z2, mask, 32);
    float aw = e2 / Z2;
    out[NPIX + ((b*ND + d)*NH + h)*NW + w] = aw;

    float bv = aw; int bi = d;
    #pragma unroll
    for (int mask = 1; mask < 32; mask <<= 1) {
        float ov = __shfl_xor(bv, mask, 32);
        int   oi = __shfl_xor(bi, mask, 32);
        if (ov > bv || (ov == bv && oi < bi)) { bv = ov; bi = oi; }
    }
    float dsel = __shfl(depth, bi, 32);
    if (d == 0) out[p] = dsel;
}

// ---------------------------------------------------------------------------
// Fallback whole-kernel (original layout) if ws too small
// ---------------------------------------------------------------------------
__global__ __launch_bounds__(256) void mvs_kernel(
    const float* __restrict__ ref_feats,
    const float* __restrict__ src_feats,
    const float* __restrict__ depth_hypo,
    const float* __restrict__ w_reg,
    const float* __restrict__ pw,
    float* __restrict__ out)
{
    int tid = blockIdx.x * 256 + threadIdx.x;
    int d = threadIdx.x & 31;
    int p = tid >> 5;
    if (p >= NPIX) return;
    int w = p % NW;
    int h = (p / NW) % NH;
    int b = p / (NW*NH);
    float xf = (float)w, yf = (float)h;
    float depth = depth_hypo[((b*ND + d)*NH + h)*NW + w];
    float wr[NG];
    #pragma unroll
    for (int g = 0; g < NG; ++g) wr[g] = w_reg[g];
    float logacc = 0.f;
    float cwsum  = 1e-8f;
    for (int v = 0; v < NV; ++v) {
        const float* RT = pw + (b*NV + v)*12;
        double dd  = (double)depth;
        double px_ = ((double)RT[0]*(double)xf + (double)RT[1]*(double)yf + (double)RT[2])*dd + (double)RT[9];
        double py_ = ((double)RT[3]*(double)xf + (double)RT[4]*(double)yf + (double)RT[5])*dd + (double)RT[10];
        double pz_ = ((double)RT[6]*(double)xf + (double)RT[7]*(double)yf + (double)RT[8])*dd + (double)RT[11];
        if (pz_ == 0.0) pz_ = 1e-9;
        double pxd = px_/pz_, pyd = py_/pz_;
        double x0d = floor(pxd), y0d = floor(pyd);
        int x0i = (int)x0d, y0i = (int)y0d;
        int x1i = x0i + 1,  y1i = y0i + 1;
        float wx = (float)(pxd - x0d), wy = (float)(pyd - y0d);
        float vx0 = (x0i >= 0 && x0i < NW) ? 1.f : 0.f;
        float vx1 = (x1i >= 0 && x1i < NW) ? 1.f : 0.f;
        float vy0 = (y0i >= 0 && y0i < NH) ? 1.f : 0.f;
        float vy1 = (y1i >= 0 && y1i < NH) ? 1.f : 0.f;
        float w00 = (1.f-wx)*(1.f-wy) * vx0*vy0;
        float w01 = wx*(1.f-wy)       * vx1*vy0;
        float w10 = (1.f-wx)*wy       * vx0*vy1;
        float w11 = wx*wy             * vx1*vy1;
        int xc0 = min(max(x0i,0),NW-1), xc1 = min(max(x1i,0),NW-1);
        int yc0 = min(max(y0i,0),NH-1), yc1 = min(max(y1i,0),NH-1);
        int i00 = yc0*NW+xc0, i01 = yc0*NW+xc1;
        int i10 = yc1*NW+xc0, i11 = yc1*NW+xc1;
        const float* sb = src_feats + ((v*NB + b)*NC)*HW;
        const float* rb = ref_feats + ((v*NB + b)*NC)*HW + h*NW + w;
        float acc[NG];
        #pragma unroll
        for (int g = 0; g < NG; ++g) acc[g] = 0.f;
        #pragma unroll
        for (int c = 0; c < NC; ++c) {
            const float* scp = sb + c*HW;
            float f = w00*scp[i00] + w01*scp[i01] + w10*scp[i10] + w11*scp[i11];
            acc[c>>2] += f * rb[c*HW];
        }
        float s = 0.f, t = 0.f;
        #pragma unroll
        for (int g = 0; g < NG; ++g) {
            float cf = 0.25f*acc[g];
            s += cf;
            t += cf*wr[g];
        }
        float m = s;
        #pragma unroll
        for (int mask = 1; mask < 32; mask <<= 1)
            m = fmaxf(m, __shfl_xor(m, mask, 32));
        float e = expf(s - m);
        float Z = e;
        #pragma unroll
        for (int mask = 1; mask < 32; mask <<= 1)
            Z += __shfl_xor(Z, mask, 32);
        float cw = 1.f / Z;
        logacc += cw * t;
        cwsum  += cw;
    }
    float logit = logacc / (cwsum + 1e-7f);
    float m2 = logit;
    #pragma unroll
    for (int mask = 1; mask < 32; mask <<= 1)
        m2 = fmaxf(m2, __shfl_xor(m2, mask, 32));
    float e2 = expf(logit - m2);
    float Z2 = e2;
    #pragma unroll
    for (int mask = 1; mask < 32; mask <<= 1)
        Z2 += __shfl_xor(Z2, mask, 32);
    float aw = e2 / Z2;
    out[NPIX + ((b*ND + d)*NH + h)*NW + w] = aw;
    float bv = aw; int bi = d;
    #pragma unroll
    for (int mask = 1; mask < 32; mask <<= 1) {
        float ov = __shfl_xor(bv, mask, 32);
        int   oi = __shfl_xor(bi, mask, 32);
        if (ov > bv || (ov == bv && oi < bi)) { bv = ov; bi = oi; }
    }
    float dsel = __shfl(depth, bi, 32);
    if (d == 0) out[p] = dsel;
}

extern "C" void kernel_launch(void* const* d_in, const int* in_sizes, int n_in,
                              void* d_out, int out_size, void* d_ws, size_t ws_size,
                              hipStream_t stream) {
    const float* ref_feats  = (const float*)d_in[0];
    const float* src_feats  = (const float*)d_in[1];
    const float* proj       = (const float*)d_in[2];
    const float* depth_hypo = (const float*)d_in[3];
    const float* w_reg      = (const float*)d_in[4];
    float* out = (float*)d_out;

    size_t need = (size_t)2*FEATSZ*sizeof(float) + 96*sizeof(float);
    if (ws_size >= need) {
        float* srcT = (float*)d_ws;
        float* refT = srcT + FEATSZ;
        float* pw   = refT + FEATSZ;
        hipLaunchKernelGGL(proj_setup_kernel, dim3(1), dim3(64), 0, stream, proj, pw);
        dim3 tg(HW/64, NV*NB);
        hipLaunchKernelGGL(transpose_kernel, tg, dim3(256), 0, stream, src_feats, srcT);
        hipLaunchKernelGGL(transpose_kernel, tg, dim3(256), 0, stream, ref_feats, refT);
        hipLaunchKernelGGL(mvs_kernel_t, dim3((NPIX*ND)/256), dim3(256), 0, stream,
                           refT, srcT, depth_hypo, w_reg, pw, out);
    } else {
        float* pw = (float*)d_ws;
        hipLaunchKernelGGL(proj_setup_kernel, dim3(1), dim3(64), 0, stream, proj, pw);
        hipLaunchKernelGGL(mvs_kernel, dim3((NPIX*ND)/256), dim3(256), 0, stream,
                           ref_feats, src_feats, depth_hypo, w_reg, pw, out);
    }
}